// Round 1
// baseline (123.944 us; speedup 1.0000x reference)
//
#include <hip/hip_runtime.h>
#include <hip/hip_bf16.h>

// cos(2*pi*t/8), t = 0..7
__device__ const float C8[8] = {
    1.0f, 0.70710678118654752f, 0.0f, -0.70710678118654752f,
   -1.0f, -0.70710678118654752f, 0.0f, 0.70710678118654752f
};

// ---------------- prep: gain(6) -> K0[64], K1[64] ----------------
__global__ __launch_bounds__(64) void k_prep(const float* __restrict__ gain,
                                             float* __restrict__ K0,
                                             float* __restrict__ K1) {
    __shared__ float m0[40], m1[40];
    int t = threadIdx.x;
    if (t < 40) {
        int ky = t / 5, kx = t % 5;
        int kyp = (ky < 8 - ky) ? ky : (8 - ky);
        float r = sqrtf((float)(kyp * kyp + kx * kx)) / (sqrtf(32.0f) + 1e-8f);
        r = fminf(fmaxf(r, 0.0f), 1.0f);
        float wv[6], wsum = 0.0f;
        #pragma unroll
        for (int i = 0; i < 6; ++i) {
            float c = 0.2f * (float)i;
            float v = fmaxf(1.0f - fabsf(r - c) * 5.0f, 0.0f);
            wv[i] = v; wsum += v;
        }
        float inv = 1.0f / (wsum + 1e-8f);
        float acc = 0.0f;
        #pragma unroll
        for (int i = 0; i < 6; ++i) acc += wv[i] * inv * gain[i];
        float mask = fmaxf(acc, 0.0f);
        m0[t] = mask;
        m1[t] = (r >= 0.6f) ? mask : 0.0f;
    }
    __syncthreads();
    int a = t >> 3, b = t & 7;
    float s0 = 0.0f, s1 = 0.0f;
    for (int ky = 0; ky < 8; ++ky) {
        for (int kx = 0; kx < 8; ++kx) {
            int kxh = (kx <= 4) ? kx : (8 - kx);
            float c = C8[(ky * a + kx * b) & 7];
            s0 += m0[ky * 5 + kxh] * c;
            s1 += m1[ky * 5 + kxh] * c;
        }
    }
    K0[t] = s0 * (1.0f / 64.0f);
    K1[t] = s1 * (1.0f / 64.0f);
}

// ---------------- channel mean: x(4,32,512,512) -> xm(4,512,512) ----------------
__global__ __launch_bounds__(256) void k_mean(const float* __restrict__ x,
                                              float* __restrict__ xm) {
    int idx = blockIdx.x * 256 + threadIdx.x;   // float4 index, 262144 total
    int b = idx >> 16;                          // 65536 float4 per batch plane
    int rem = idx & 65535;
    const float4* xp = (const float4*)x + (size_t)b * 32 * 65536 + rem;
    float4 acc = {0.f, 0.f, 0.f, 0.f};
    #pragma unroll 8
    for (int c = 0; c < 32; ++c) {
        float4 v = xp[(size_t)c * 65536];
        acc.x += v.x; acc.y += v.y; acc.z += v.z; acc.w += v.w;
    }
    const float s = 1.0f / 32.0f;
    acc.x *= s; acc.y *= s; acc.z *= s; acc.w *= s;
    ((float4*)xm)[idx] = acc;
}

// ---------------- edge strength per patch: xm -> es(4,64,64) ----------------
__global__ __launch_bounds__(256) void k_edge(const float* __restrict__ xm,
                                              float* __restrict__ es) {
    int b = blockIdx.x >> 6;
    int hti = blockIdx.x & 63;
    int t = threadIdx.x;
    int w = t & 63;     // patch column
    int q = t >> 6;     // quarter: rows q*2, q*2+1 of the patch
    const float* base = xm + (size_t)b * 512 * 512;
    float partial = 0.0f;
    for (int ry = 0; ry < 2; ++ry) {
        int y = hti * 8 + q * 2 + ry;
        for (int x0 = 0; x0 < 8; ++x0) {
            int xx = w * 8 + x0;
            float n[3][3];
            #pragma unroll
            for (int dy = -1; dy <= 1; ++dy) {
                #pragma unroll
                for (int dx = -1; dx <= 1; ++dx) {
                    int yy = y + dy, xc = xx + dx;
                    float v = 0.0f;
                    if (yy >= 0 && yy < 512 && xc >= 0 && xc < 512)
                        v = base[yy * 512 + xc];
                    n[dy + 1][dx + 1] = v;
                }
            }
            float gx = (n[0][2] - n[0][0]) + 2.0f * (n[1][2] - n[1][0]) + (n[2][2] - n[2][0]);
            float gy = (n[2][0] - n[0][0]) + 2.0f * (n[2][1] - n[0][1]) + (n[2][2] - n[0][2]);
            partial += sqrtf(gx * gx + gy * gy + 1e-6f);
        }
    }
    __shared__ float sred[256];
    sred[t] = partial;
    __syncthreads();
    if (t < 64) {
        float s = sred[t] + sred[t + 64] + sred[t + 128] + sred[t + 192];
        es[((size_t)b * 64 + hti) * 64 + t] = s * (1.0f / 64.0f);
    }
}

// ---------------- per-batch normalize: es -> f = (ec - 1) ----------------
__global__ __launch_bounds__(256) void k_coeff(const float* __restrict__ es,
                                               float* __restrict__ f) {
    int b = blockIdx.x;
    int t = threadIdx.x;
    const float* e = es + (size_t)b * 4096;
    float mn = 1e30f, mx = -1e30f;
    for (int i = t; i < 4096; i += 256) {
        float v = e[i];
        mn = fminf(mn, v); mx = fmaxf(mx, v);
    }
    #pragma unroll
    for (int off = 32; off > 0; off >>= 1) {
        mn = fminf(mn, __shfl_down(mn, off));
        mx = fmaxf(mx, __shfl_down(mx, off));
    }
    __shared__ float smn[4], smx[4];
    if ((t & 63) == 0) { smn[t >> 6] = mn; smx[t >> 6] = mx; }
    __syncthreads();
    mn = fminf(fminf(smn[0], smn[1]), fminf(smn[2], smn[3]));
    mx = fmaxf(fmaxf(smx[0], smx[1]), fmaxf(smx[2], smx[3]));
    float scale = 0.5f / (mx - mn + 1e-6f);
    for (int i = t; i < 4096; i += 256) {
        f[(size_t)b * 4096 + i] = (e[i] - mn) * scale;
    }
}

// ---------------- main: per-patch circular conv with K_eff = K0 + f*K1 ----------------
__global__ __launch_bounds__(256) void k_main(const float* __restrict__ x,
                                              const float* __restrict__ Kg,
                                              const float* __restrict__ f,
                                              float* __restrict__ out) {
    // grid: 2048 = b(4) * hti(64) * cg(8); block 256: w(64) x cloc(4)
    int blk = blockIdx.x;
    int cg = blk & 7;
    int hti = (blk >> 3) & 63;
    int b = blk >> 9;
    int t = threadIdx.x;
    int w = t & 63;
    int c = cg * 4 + (t >> 6);

    float fc = f[((size_t)b * 64 + hti) * 64 + w];

    float K[64];
    #pragma unroll
    for (int i = 0; i < 64; ++i) K[i] = Kg[i] + fc * Kg[64 + i];

    size_t ofs = (((size_t)(b * 32 + c) * 512) + hti * 8) * 512 + w * 8;
    const float* src = x + ofs;
    float* dst = out + ofs;

    float acc[8][8];
    #pragma unroll
    for (int y = 0; y < 8; ++y)
        #pragma unroll
        for (int xx = 0; xx < 8; ++xx) acc[y][xx] = 0.0f;

    #pragma unroll
    for (int a = 0; a < 8; ++a) {
        float4 p0 = *(const float4*)(src + a * 512);
        float4 p1 = *(const float4*)(src + a * 512 + 4);
        float pr[8] = {p0.x, p0.y, p0.z, p0.w, p1.x, p1.y, p1.z, p1.w};
        #pragma unroll
        for (int y = 0; y < 8; ++y) {
            const int krow = ((y - a) & 7) * 8;
            #pragma unroll
            for (int xx = 0; xx < 8; ++xx) {
                float s = acc[y][xx];
                #pragma unroll
                for (int bb = 0; bb < 8; ++bb) {
                    s += pr[bb] * K[krow + ((xx - bb) & 7)];
                }
                acc[y][xx] = s;
            }
        }
    }
    #pragma unroll
    for (int y = 0; y < 8; ++y) {
        float4 o0 = {acc[y][0], acc[y][1], acc[y][2], acc[y][3]};
        float4 o1 = {acc[y][4], acc[y][5], acc[y][6], acc[y][7]};
        *(float4*)(dst + y * 512) = o0;
        *(float4*)(dst + y * 512 + 4) = o1;
    }
}

extern "C" void kernel_launch(void* const* d_in, const int* in_sizes, int n_in,
                              void* d_out, int out_size, void* d_ws, size_t ws_size,
                              hipStream_t stream) {
    const float* x    = (const float*)d_in[0];   // (4,32,512,512)
    const float* gain = (const float*)d_in[1];   // (1,6)
    float* out = (float*)d_out;
    float* ws = (float*)d_ws;

    float* Kg = ws;                      // 128 floats: K0 | K1
    float* f  = ws + 128;                // 4*4096
    float* es = ws + 128 + 16384;        // 4*4096
    float* xm = ws + 128 + 2 * 16384;    // 4*512*512

    hipLaunchKernelGGL(k_prep, dim3(1), dim3(64), 0, stream, gain, Kg, Kg + 64);
    hipLaunchKernelGGL(k_mean, dim3(1024), dim3(256), 0, stream, x, xm);
    hipLaunchKernelGGL(k_edge, dim3(256), dim3(256), 0, stream, xm, es);
    hipLaunchKernelGGL(k_coeff, dim3(4), dim3(256), 0, stream, es, f);
    hipLaunchKernelGGL(k_main, dim3(2048), dim3(256), 0, stream, x, Kg, f, out);
}